// Round 7
// baseline (1551.057 us; speedup 1.0000x reference)
//
#include <hip/hip_runtime.h>
#include <math.h>

// Problem constants
#define KCL    8192      // clusters
#define DIM    64        // embedding dim
#define NPTS   32768     // B*H*W
#define HW     1024      // H*W
#define PLANE  65536     // D*H*W (per-batch stride in z)
#define SPLITS 16
#define CBLK   (KCL / SPLITS)    // 512 clusters per split
#define PHROWS 128               // clusters staged per phase (32 KB)
#define NPH    (CBLK / PHROWS)   // 4 phases

// -------------------- e2[k] = ||embedding[k]||^2 --------------------
__global__ __launch_bounds__(256) void e2_kernel(const float* __restrict__ emb,
                                                 float* __restrict__ e2) {
    int k = blockIdx.x * 256 + threadIdx.x;
    const float4* row = (const float4*)(emb + (size_t)k * DIM);
    float s = 0.f;
#pragma unroll
    for (int i = 0; i < DIM / 4; ++i) {
        float4 v = row[i];
        s += v.x * v.x + v.y * v.y + v.z * v.z + v.w * v.w;
    }
    e2[k] = s;
}

// -------------------- distance + argmin --------------------
// 2 points per lane (z rows in 128 VGPRs). e-side staged in LDS, read as
// wave-uniform broadcast ds_read_b128 (same-address -> conflict-free);
// each 16B feeds 8 fmacs. 8 rotating accumulators break the dep chain.
__global__ __launch_bounds__(256, 3) void vq_dist(
    const float* __restrict__ z, const float* __restrict__ emb,
    const float* __restrict__ e2g, float* __restrict__ bestO,
    int* __restrict__ kbestO) {
    __shared__ __align__(16) float elds[PHROWS * DIM];   // 32 KB = 2048 float4
    __shared__ float e2lds[PHROWS];

    const int t  = threadIdx.x;
    const int ks = blockIdx.x & (SPLITS - 1);   // cluster slice (L2-local per XCD)
    const int pb = blockIdx.x >> 4;             // 0..63 : 512-point tile
    const int pA = pb * 512 + t;                // point A
    const int b  = pb >> 1;
    const int hw0 = (pb & 1) * 512;
    const float* zbase = z + (size_t)b * PLANE + hw0 + t;

    float zA[DIM], zB[DIM];
#pragma unroll
    for (int d = 0; d < DIM; ++d) {
        zA[d] = zbase[(size_t)d * HW];
        zB[d] = zbase[(size_t)d * HW + 256];
    }

    float bestA = 3.4e38f, bestB = 3.4e38f;
    int   bkA = 0, bkB = 0;

    for (int ph = 0; ph < NPH; ++ph) {
        const int kbase = ks * CBLK + ph * PHROWS;
        __syncthreads();
        {   // cooperative stage: 128 rows = 2048 float4, 8 per thread (coalesced)
            const float4* src = (const float4*)(emb + (size_t)kbase * DIM);
            float4* dst = (float4*)elds;
#pragma unroll
            for (int i = 0; i < 8; ++i) dst[t + 256 * i] = src[t + 256 * i];
            if (t < PHROWS) e2lds[t] = e2g[kbase + t];
        }
        __syncthreads();

        for (int c = 0; c < PHROWS; ++c) {
            const float4* er4 = (const float4*)(elds + (c << 6));
            float aA[4] = {0.f, 0.f, 0.f, 0.f};
            float aB[4] = {0.f, 0.f, 0.f, 0.f};
#pragma unroll
            for (int q = 0; q < 16; ++q) {
                float4 ev = er4[q];     // uniform address -> LDS broadcast
                aA[0] = fmaf(ev.x, zA[4 * q + 0], aA[0]);
                aB[0] = fmaf(ev.x, zB[4 * q + 0], aB[0]);
                aA[1] = fmaf(ev.y, zA[4 * q + 1], aA[1]);
                aB[1] = fmaf(ev.y, zB[4 * q + 1], aB[1]);
                aA[2] = fmaf(ev.z, zA[4 * q + 2], aA[2]);
                aB[2] = fmaf(ev.z, zB[4 * q + 2], aB[2]);
                aA[3] = fmaf(ev.w, zA[4 * q + 3], aA[3]);
                aB[3] = fmaf(ev.w, zB[4 * q + 3], aB[3]);
            }
            float accA = (aA[0] + aA[1]) + (aA[2] + aA[3]);
            float accB = (aB[0] + aB[1]) + (aB[2] + aB[3]);
            float e2v  = e2lds[c];
            float dA = fmaf(-2.f, accA, e2v);
            float dB = fmaf(-2.f, accB, e2v);
            int kk = kbase + c;
            if (dA < bestA) { bestA = dA; bkA = kk; }   // strict < : first-index
            if (dB < bestB) { bestB = dB; bkB = kk; }
        }
    }
    bestO[ks * NPTS + pA]        = bestA;
    kbestO[ks * NPTS + pA]       = bkA;
    bestO[ks * NPTS + pA + 256]  = bestB;
    kbestO[ks * NPTS + pA + 256] = bkB;
}

// -------------------- merge splits + idx/counts/zq/loss --------------------
__global__ __launch_bounds__(256) void merge_kernel(
    const float* __restrict__ z, const float* __restrict__ emb,
    const float* __restrict__ bestO, const int* __restrict__ kbestO,
    float* __restrict__ counts, float* __restrict__ loss_ws,
    float* __restrict__ zq_out, float* __restrict__ idx_out,
    int* __restrict__ kbest) {
    const int t = threadIdx.x;
    const int p = blockIdx.x * 256 + t;
    float best = 3.4e38f;
    int   bk   = 0;
#pragma unroll
    for (int s = 0; s < SPLITS; ++s) {      // ascending split = first-index ties
        float d = bestO[s * NPTS + p];
        int   k = kbestO[s * NPTS + p];
        if (d < best) { best = d; bk = k; }
    }
    idx_out[p] = (float)bk;
    kbest[p]   = bk;
    atomicAdd(&counts[bk], 1.0f);

    const int b = p >> 10, hw = p & 1023;
    const float* er = emb + ((size_t)bk << 6);
    float lsum = 0.f;
#pragma unroll
    for (int d = 0; d < DIM; ++d) {
        size_t g  = (size_t)b * PLANE + (size_t)d * HW + hw;
        float zvv = z[g];
        float ev  = er[d];
        zq_out[g] = ev;                     // coalesced across lanes
        float df  = ev - zvv;
        lsum = fmaf(df, df, lsum);
    }
#pragma unroll
    for (int off = 32; off > 0; off >>= 1) lsum += __shfl_xor(lsum, off);
    if ((t & 63) == 0) atomicAdd(loss_ws, lsum);
}

// -------------------- exclusive scan of counts -> offs --------------------
__global__ __launch_bounds__(256) void scan_kernel(const float* __restrict__ counts,
                                                   int* __restrict__ offs) {
    __shared__ int part[256];
    __shared__ int partsum[256];
    const int t = threadIdx.x;
    int loc[32];
    int s = 0;
#pragma unroll
    for (int i = 0; i < 32; ++i) { loc[i] = s; s += (int)counts[t * 32 + i]; }
    part[t] = s;
    __syncthreads();
    if (t == 0) {
        int a = 0;
        for (int i = 0; i < 256; ++i) { partsum[i] = a; a += part[i]; }
    }
    __syncthreads();
    const int off0 = partsum[t];
#pragma unroll
    for (int i = 0; i < 32; ++i) offs[t * 32 + i] = off0 + loc[i];
}

// -------------------- fill per-cluster point lists --------------------
__global__ __launch_bounds__(256) void fill_kernel(const int* __restrict__ kbest,
                                                   const int* __restrict__ offs,
                                                   int* __restrict__ cursor,
                                                   int* __restrict__ plist) {
    const int p = blockIdx.x * 256 + threadIdx.x;
    const int k = kbest[p];
    int pos = atomicAdd(&cursor[k], 1);
    plist[offs[k] + pos] = p;
}

// -------------------- EMA finalize (gathers z sums directly) --------------------
__global__ __launch_bounds__(256) void ema_kernel(
    const float* __restrict__ z, const float* __restrict__ ema_cs,
    const float* __restrict__ ema_avg, const float* __restrict__ counts,
    const int* __restrict__ offs, const int* __restrict__ plist,
    float* __restrict__ out_ncs, float* __restrict__ out_navg,
    float* __restrict__ out_nemb) {
    const int tid = blockIdx.x * 256 + threadIdx.x;   // 0..131071 (K*16)
    const int k = tid >> 4, q = tid & 15;             // q = dim quad
    const int off = offs[k];
    const int cnt = (int)counts[k];

    float s0 = 0.f, s1 = 0.f, s2 = 0.f, s3 = 0.f;
    for (int i = 0; i < cnt; ++i) {
        int p = plist[off + i];
        int b = p >> 10, hw = p & 1023;
        const float* zp = z + (size_t)b * PLANE + (size_t)(4 * q) * HW + hw;
        s0 += zp[0];
        s1 += zp[HW];
        s2 += zp[2 * HW];
        s3 += zp[3 * HW];
    }

    float ncs = 0.99f * ema_cs[k] + 0.01f * counts[k];
    float den = ncs + 1e-5f;
    float4 ea = ((const float4*)ema_avg)[tid];
    float4 na, ne;
    na.x = 0.99f * ea.x + 0.01f * s0;
    na.y = 0.99f * ea.y + 0.01f * s1;
    na.z = 0.99f * ea.z + 0.01f * s2;
    na.w = 0.99f * ea.w + 0.01f * s3;
    ne.x = na.x / den; ne.y = na.y / den; ne.z = na.z / den; ne.w = na.w / den;
    ((float4*)out_navg)[tid] = na;
    ((float4*)out_nemb)[tid] = ne;
    if (q == 0) out_ncs[k] = ncs;
}

// -------------------- scalars: loss + perplexity --------------------
__global__ __launch_bounds__(256) void scalars_kernel(
    const float* __restrict__ counts, const float* __restrict__ loss_ws,
    float* __restrict__ out_loss, float* __restrict__ out_perp) {
    __shared__ float red[4];
    float s = 0.f;
    for (int k = threadIdx.x; k < KCL; k += 256) {
        float p = counts[k] * (1.0f / (float)NPTS);
        s += p * logf(p + 1e-10f);
    }
#pragma unroll
    for (int off = 32; off > 0; off >>= 1) s += __shfl_xor(s, off, 64);
    if ((threadIdx.x & 63) == 0) red[threadIdx.x >> 6] = s;
    __syncthreads();
    if (threadIdx.x == 0) {
        float tot = red[0] + red[1] + red[2] + red[3];
        out_perp[0] = expf(-tot);
        out_loss[0] = 0.25f * loss_ws[0] / (float)(NPTS * DIM);
    }
}

extern "C" void kernel_launch(void* const* d_in, const int* in_sizes, int n_in,
                              void* d_out, int out_size, void* d_ws, size_t ws_size,
                              hipStream_t stream) {
    (void)in_sizes; (void)n_in; (void)out_size; (void)ws_size;
    const float* z       = (const float*)d_in[0];
    const float* emb     = (const float*)d_in[1];
    const float* ema_cs  = (const float*)d_in[2];
    const float* ema_avg = (const float*)d_in[3];

    float* out0      = (float*)d_out;            // z_quantized_st  [2097152]
    float* out_loss  = out0 + 2097152;           // loss            [1]
    float* out_perp  = out_loss + 1;             // perplexity      [1]
    float* out_idx   = out_perp + 1;             // encoding_indices[32768]
    float* out_nemb  = out_idx + NPTS;           // new_embedding   [524288]
    float* out_ncs   = out_nemb + KCL * DIM;     // new_cluster_size[8192]
    float* out_navg  = out_ncs + KCL;            // new_embedding_avg[524288]

    // workspace layout
    float* e2_ws     = (float*)d_ws;             // [8192]
    float* counts_ws = e2_ws + KCL;              // [8192]
    int*   cursor_ws = (int*)(counts_ws + KCL);  // [8192]
    float* loss_ws   = (float*)(cursor_ws + KCL);// [1]
    int*   offs_ws   = (int*)(loss_ws + 1);      // [8192]
    int*   plist_ws  = offs_ws + KCL;            // [32768]
    int*   kbest_ws  = plist_ws + NPTS;          // [32768]

    // split-argmin scratch overlaid on output regions consumed before ema writes
    float* bestO  = out_nemb;                    // [SPLITS*NPTS] = 524288 floats
    int*   kbestO = (int*)out_navg;              // [524288] ints

    // zero counts + cursor + loss (contiguous)
    hipMemsetAsync((void*)counts_ws, 0, (size_t)(KCL + KCL + 1) * sizeof(float), stream);

    e2_kernel<<<KCL / 256, 256, 0, stream>>>(emb, e2_ws);
    vq_dist<<<(NPTS / 512) * SPLITS, 256, 0, stream>>>(z, emb, e2_ws, bestO, kbestO);
    merge_kernel<<<NPTS / 256, 256, 0, stream>>>(z, emb, bestO, kbestO, counts_ws,
                                                 loss_ws, out0, out_idx, kbest_ws);
    scan_kernel<<<1, 256, 0, stream>>>(counts_ws, offs_ws);
    fill_kernel<<<NPTS / 256, 256, 0, stream>>>(kbest_ws, offs_ws, cursor_ws, plist_ws);
    ema_kernel<<<KCL * 16 / 256, 256, 0, stream>>>(z, ema_cs, ema_avg, counts_ws,
                                                   offs_ws, plist_ws, out_ncs,
                                                   out_navg, out_nemb);
    scalars_kernel<<<1, 256, 0, stream>>>(counts_ws, loss_ws, out_loss, out_perp);
}

// Round 9
// 667.758 us; speedup vs baseline: 2.3228x; 2.3228x over previous
//
#include <hip/hip_runtime.h>
#include <math.h>

// Problem constants
#define KCL    8192      // clusters
#define DIM    64        // embedding dim
#define NPTS   32768     // B*H*W
#define HW     1024      // H*W
#define PLANE  65536     // D*H*W (per-batch stride in z)
#define SPLITS 4
#define CBLK   (KCL / SPLITS)    // 2048 clusters per split
#define ESTR   160               // skewed e-row stride (floats)

// -------------------- e2[k] = ||embedding[k]||^2 --------------------
__global__ __launch_bounds__(256) void e2_kernel(const float* __restrict__ emb,
                                                 float* __restrict__ e2) {
    int k = blockIdx.x * 256 + threadIdx.x;
    const float4* row = (const float4*)(emb + (size_t)k * DIM);
    float s = 0.f;
#pragma unroll
    for (int i = 0; i < DIM / 4; ++i) {
        float4 v = row[i];
        s += v.x * v.x + v.y * v.y + v.z * v.z + v.w * v.w;
    }
    e2[k] = s;
}

// -------------------- distance + argmin: 16x8 register tile --------------------
// Block tile: 256 points x 128 clusters; thread (tp,tc) = (t>>4, t&15) computes
// 16 pts x 8 cls. z LDS [32d][256p] (broadcast reads, 2-way free); e LDS
// [32d][c + 4*(c>>4)] skewed (16-lane reads exactly 2-way = free).
// K split 4 ways; d split in 2 chunks of 32 accumulated into persistent acc.
__global__ __launch_bounds__(256, 2) void vq_dist(
    const float* __restrict__ z, const float* __restrict__ emb,
    const float* __restrict__ e2g, float* __restrict__ bestO,
    int* __restrict__ kbestO) {
    __shared__ __align__(16) float zl[32 * 256];   // 32 KB
    __shared__ __align__(16) float el[32 * ESTR];  // 20 KB
    __shared__ float e2l[128];

    const int t    = threadIdx.x;
    const int tc   = t & 15, tp = t >> 4;
    const int lane = t & 63, w = t >> 6;
    const int ks   = blockIdx.x & (SPLITS - 1);
    const int pb   = blockIdx.x >> 2;
    const int p0   = pb * 256;
    const int b    = p0 >> 10, hw0 = p0 & 1023;

    // staging geometry (e): c = t&127, half = t>>7
    const int sc   = t & 127, shalf = t >> 7;
    const int scw  = sc + 4 * (sc >> 4);
    // compute geometry
    const int ebase = tc * 8 + (tc >> 1) * 4;   // skew uniform over this thread's 8 cls
    const int zbase = tp * 16;

    float best[16]; int bestk[16];
#pragma unroll
    for (int i = 0; i < 16; ++i) { best[i] = 3.4e38f; bestk[i] = 0; }

    for (int kc = 0; kc < CBLK / 128; ++kc) {
        const int k0 = ks * CBLK + kc * 128;

        float acc[16][8];
#pragma unroll
        for (int i = 0; i < 16; ++i)
#pragma unroll
            for (int j = 0; j < 8; ++j) acc[i][j] = 0.f;

        for (int dc = 0; dc < 2; ++dc) {
            __syncthreads();
            {   // stage z chunk: [dl][p], 8 float4/thread, coalesced
                const float* zsrc = z + (size_t)b * PLANE + (size_t)(dc * 32) * HW + hw0;
#pragma unroll
                for (int i = 0; i < 8; ++i) {
                    int dl = w + 4 * i;
                    *(float4*)&zl[dl * 256 + lane * 4] =
                        *(const float4*)(zsrc + (size_t)dl * HW + lane * 4);
                }
            }
            {   // stage e chunk transposed+skewed: 4 float4/thread
                const float* esrc = emb + (size_t)(k0 + sc) * DIM + dc * 32 + shalf * 16;
#pragma unroll
                for (int j = 0; j < 4; ++j) {
                    float4 v = *(const float4*)(esrc + j * 4);
                    int dl = shalf * 16 + j * 4;
                    el[(dl + 0) * ESTR + scw] = v.x;
                    el[(dl + 1) * ESTR + scw] = v.y;
                    el[(dl + 2) * ESTR + scw] = v.z;
                    el[(dl + 3) * ESTR + scw] = v.w;
                }
                if (dc == 0 && t < 128) e2l[t] = e2g[k0 + t];
            }
            __syncthreads();

#pragma unroll 4
            for (int dl = 0; dl < 32; ++dl) {
                float zf[16], ef[8];
                *(float4*)&zf[0]  = *(const float4*)&zl[dl * 256 + zbase];
                *(float4*)&zf[4]  = *(const float4*)&zl[dl * 256 + zbase + 4];
                *(float4*)&zf[8]  = *(const float4*)&zl[dl * 256 + zbase + 8];
                *(float4*)&zf[12] = *(const float4*)&zl[dl * 256 + zbase + 12];
                *(float4*)&ef[0]  = *(const float4*)&el[dl * ESTR + ebase];
                *(float4*)&ef[4]  = *(const float4*)&el[dl * ESTR + ebase + 4];
#pragma unroll
                for (int i = 0; i < 16; ++i)
#pragma unroll
                    for (int j = 0; j < 8; ++j)
                        acc[i][j] = fmaf(zf[i], ef[j], acc[i][j]);
            }
        }

        // distances + running argmin (ascending k, strict < = first-index ties)
#pragma unroll
        for (int j = 0; j < 8; ++j) {
            float e2v = e2l[tc * 8 + j];
            int   kk  = k0 + tc * 8 + j;
#pragma unroll
            for (int i = 0; i < 16; ++i) {
                float dist = fmaf(-2.f, acc[i][j], e2v);
                if (dist < best[i]) { best[i] = dist; bestk[i] = kk; }
            }
        }
    }

    // reduce across the 16 tc lanes (tc = low 4 lane bits)
#pragma unroll
    for (int i = 0; i < 16; ++i) {
        float bd = best[i]; int bk = bestk[i];
#pragma unroll
        for (int off = 8; off > 0; off >>= 1) {
            float od = __shfl_xor(bd, off, 16);
            int   ok = __shfl_xor(bk, off, 16);
            if (od < bd || (od == bd && ok < bk)) { bd = od; bk = ok; }
        }
        if (tc == 0) {
            int p = p0 + tp * 16 + i;
            bestO[ks * NPTS + p]  = bd;
            kbestO[ks * NPTS + p] = bk;
        }
    }
}

// -------------------- merge splits + idx/counts/zq/loss --------------------
__global__ __launch_bounds__(256) void merge_kernel(
    const float* __restrict__ z, const float* __restrict__ emb,
    const float* __restrict__ bestO, const int* __restrict__ kbestO,
    float* __restrict__ counts, float* __restrict__ loss_ws,
    float* __restrict__ zq_out, float* __restrict__ idx_out,
    int* __restrict__ kbest) {
    const int t = threadIdx.x;
    const int p = blockIdx.x * 256 + t;
    float best = 3.4e38f;
    int   bk   = 0;
#pragma unroll
    for (int s = 0; s < SPLITS; ++s) {      // ascending split = first-index ties
        float d = bestO[s * NPTS + p];
        int   k = kbestO[s * NPTS + p];
        if (d < best) { best = d; bk = k; }
    }
    idx_out[p] = (float)bk;
    kbest[p]   = bk;
    atomicAdd(&counts[bk], 1.0f);

    const int b = p >> 10, hw = p & 1023;
    const float* er = emb + ((size_t)bk << 6);
    float lsum = 0.f;
#pragma unroll
    for (int d = 0; d < DIM; ++d) {
        size_t g  = (size_t)b * PLANE + (size_t)d * HW + hw;
        float zvv = z[g];
        float ev  = er[d];
        zq_out[g] = ev;                     // coalesced across lanes
        float df  = ev - zvv;
        lsum = fmaf(df, df, lsum);
    }
#pragma unroll
    for (int off = 32; off > 0; off >>= 1) lsum += __shfl_xor(lsum, off);
    if ((t & 63) == 0) atomicAdd(loss_ws, lsum);
}

// -------------------- exclusive scan of counts -> offs --------------------
__global__ __launch_bounds__(256) void scan_kernel(const float* __restrict__ counts,
                                                   int* __restrict__ offs) {
    __shared__ int part[256];
    __shared__ int partsum[256];
    const int t = threadIdx.x;
    int loc[32];
    int s = 0;
#pragma unroll
    for (int i = 0; i < 32; ++i) { loc[i] = s; s += (int)counts[t * 32 + i]; }
    part[t] = s;
    __syncthreads();
    if (t == 0) {
        int a = 0;
        for (int i = 0; i < 256; ++i) { partsum[i] = a; a += part[i]; }
    }
    __syncthreads();
    const int off0 = partsum[t];
#pragma unroll
    for (int i = 0; i < 32; ++i) offs[t * 32 + i] = off0 + loc[i];
}

// -------------------- fill per-cluster point lists --------------------
__global__ __launch_bounds__(256) void fill_kernel(const int* __restrict__ kbest,
                                                   const int* __restrict__ offs,
                                                   int* __restrict__ cursor,
                                                   int* __restrict__ plist) {
    const int p = blockIdx.x * 256 + threadIdx.x;
    const int k = kbest[p];
    int pos = atomicAdd(&cursor[k], 1);
    plist[offs[k] + pos] = p;
}

// -------------------- EMA finalize (gathers z sums directly) --------------------
__global__ __launch_bounds__(256) void ema_kernel(
    const float* __restrict__ z, const float* __restrict__ ema_cs,
    const float* __restrict__ ema_avg, const float* __restrict__ counts,
    const int* __restrict__ offs, const int* __restrict__ plist,
    float* __restrict__ out_ncs, float* __restrict__ out_navg,
    float* __restrict__ out_nemb) {
    const int tid = blockIdx.x * 256 + threadIdx.x;   // 0..131071 (K*16)
    const int k = tid >> 4, q = tid & 15;             // q = dim quad
    const int off = offs[k];
    const int cnt = (int)counts[k];

    float s0 = 0.f, s1 = 0.f, s2 = 0.f, s3 = 0.f;
    for (int i = 0; i < cnt; ++i) {
        int p = plist[off + i];
        int b = p >> 10, hw = p & 1023;
        const float* zp = z + (size_t)b * PLANE + (size_t)(4 * q) * HW + hw;
        s0 += zp[0];
        s1 += zp[HW];
        s2 += zp[2 * HW];
        s3 += zp[3 * HW];
    }

    float ncs = 0.99f * ema_cs[k] + 0.01f * counts[k];
    float den = ncs + 1e-5f;
    float4 ea = ((const float4*)ema_avg)[tid];
    float4 na, ne;
    na.x = 0.99f * ea.x + 0.01f * s0;
    na.y = 0.99f * ea.y + 0.01f * s1;
    na.z = 0.99f * ea.z + 0.01f * s2;
    na.w = 0.99f * ea.w + 0.01f * s3;
    ne.x = na.x / den; ne.y = na.y / den; ne.z = na.z / den; ne.w = na.w / den;
    ((float4*)out_navg)[tid] = na;
    ((float4*)out_nemb)[tid] = ne;
    if (q == 0) out_ncs[k] = ncs;
}

// -------------------- scalars: loss + perplexity --------------------
__global__ __launch_bounds__(256) void scalars_kernel(
    const float* __restrict__ counts, const float* __restrict__ loss_ws,
    float* __restrict__ out_loss, float* __restrict__ out_perp) {
    __shared__ float red[4];
    float s = 0.f;
    for (int k = threadIdx.x; k < KCL; k += 256) {
        float p = counts[k] * (1.0f / (float)NPTS);
        s += p * logf(p + 1e-10f);
    }
#pragma unroll
    for (int off = 32; off > 0; off >>= 1) s += __shfl_xor(s, off, 64);
    if ((threadIdx.x & 63) == 0) red[threadIdx.x >> 6] = s;
    __syncthreads();
    if (threadIdx.x == 0) {
        float tot = red[0] + red[1] + red[2] + red[3];
        out_perp[0] = expf(-tot);
        out_loss[0] = 0.25f * loss_ws[0] / (float)(NPTS * DIM);
    }
}

extern "C" void kernel_launch(void* const* d_in, const int* in_sizes, int n_in,
                              void* d_out, int out_size, void* d_ws, size_t ws_size,
                              hipStream_t stream) {
    (void)in_sizes; (void)n_in; (void)out_size; (void)ws_size;
    const float* z       = (const float*)d_in[0];
    const float* emb     = (const float*)d_in[1];
    const float* ema_cs  = (const float*)d_in[2];
    const float* ema_avg = (const float*)d_in[3];

    float* out0      = (float*)d_out;            // z_quantized_st  [2097152]
    float* out_loss  = out0 + 2097152;           // loss            [1]
    float* out_perp  = out_loss + 1;             // perplexity      [1]
    float* out_idx   = out_perp + 1;             // encoding_indices[32768]
    float* out_nemb  = out_idx + NPTS;           // new_embedding   [524288]
    float* out_ncs   = out_nemb + KCL * DIM;     // new_cluster_size[8192]
    float* out_navg  = out_ncs + KCL;            // new_embedding_avg[524288]

    // workspace layout
    float* e2_ws     = (float*)d_ws;             // [8192]
    float* counts_ws = e2_ws + KCL;              // [8192]
    int*   cursor_ws = (int*)(counts_ws + KCL);  // [8192]
    float* loss_ws   = (float*)(cursor_ws + KCL);// [1]
    int*   offs_ws   = (int*)(loss_ws + 1);      // [8192]
    int*   plist_ws  = offs_ws + KCL;            // [32768]
    int*   kbest_ws  = plist_ws + NPTS;          // [32768]

    // split-argmin scratch overlaid on output regions consumed before ema writes
    float* bestO  = out_nemb;                    // [SPLITS*NPTS] = 131072 floats
    int*   kbestO = (int*)out_navg;              // [131072] ints

    // zero counts + cursor + loss (contiguous)
    hipMemsetAsync((void*)counts_ws, 0, (size_t)(KCL + KCL + 1) * sizeof(float), stream);

    e2_kernel<<<KCL / 256, 256, 0, stream>>>(emb, e2_ws);
    vq_dist<<<(NPTS / 256) * SPLITS, 256, 0, stream>>>(z, emb, e2_ws, bestO, kbestO);
    merge_kernel<<<NPTS / 256, 256, 0, stream>>>(z, emb, bestO, kbestO, counts_ws,
                                                 loss_ws, out0, out_idx, kbest_ws);
    scan_kernel<<<1, 256, 0, stream>>>(counts_ws, offs_ws);
    fill_kernel<<<NPTS / 256, 256, 0, stream>>>(kbest_ws, offs_ws, cursor_ws, plist_ws);
    ema_kernel<<<KCL * 16 / 256, 256, 0, stream>>>(z, ema_cs, ema_avg, counts_ws,
                                                   offs_ws, plist_ws, out_ncs,
                                                   out_navg, out_nemb);
    scalars_kernel<<<1, 256, 0, stream>>>(counts_ws, loss_ws, out_loss, out_perp);
}